// Round 2
// baseline (243.373 us; speedup 1.0000x reference)
//
#include <hip/hip_runtime.h>

// Bilinear resample: inputs (B,S,S,C) fp32, offsets (B,S,S,2) fp32 -> out (B,S,S,C)
// B=16, S=128, C=128. Memory-bound gather with near-identity sampling grid.
//
// Revision under test (round-1 bench was an infra failure, re-running):
// XCD-chunked block swizzle so each XCD's private L2 owns a contiguous pixel
// slab (= 2 whole batches) -> all 4x bilinear tap reuse is intra-L2, no
// cross-XCD duplicate HBM fetch. Output stored nontemporally so 128 MiB of
// streaming writes don't evict the input window from L2.

constexpr int S = 128;
constexpr int CVEC = 32;          // C/4 = 128/4 float4 groups per pixel
constexpr int PIX_PER_BLOCK = 8;  // 256 threads / 32 threads-per-pixel
constexpr int NXCD = 8;

typedef float f32x4 __attribute__((ext_vector_type(4)));

__global__ __launch_bounds__(256) void resample_kernel(
    const float2* __restrict__ offsets2, // (B*S*S) float2
    const float4* __restrict__ inputs4,  // (B, S, S, C/4) as float4
    float4* __restrict__ out4,           // (B, S, S, C/4)
    int blocks_per_xcd)                  // gridDim.x / 8 (host guarantees divisible)
{
    // Hardware block b is assumed to dispatch to XCD b%8 (round-robin
    // heuristic; affects only locality, never correctness). Chunked remap:
    // XCD x processes contiguous work ids [x*q, (x+1)*q) -> contiguous
    // pixel slab -> 2 full independent batches per XCD.
    const int wg = (blockIdx.x % NXCD) * blocks_per_xcd + blockIdx.x / NXCD;

    const int tid    = threadIdx.x;
    const int lane_c = tid & 31;       // channel-group index (0..31)
    const int pix    = wg * PIX_PER_BLOCK + (tid >> 5);  // (b*S + i)*S + j

    const int j   = pix & (S - 1);
    const int rem = pix >> 7;          // b*S + i
    const int i   = rem & (S - 1);
    const int b   = rem >> 7;

    // Per-pixel coords & weights (computed redundantly by the 32 lanes).
    const float2 off = offsets2[pix];  // off.x = oy, off.y = ox
    float y = fminf(fmaxf((float)i + off.x, 0.0f), (float)(S - 1));
    float x = fminf(fmaxf((float)j + off.y, 0.0f), (float)(S - 1));

    const float y0f = floorf(y);
    const float x0f = floorf(x);
    const int y0 = (int)y0f;
    const int x0 = (int)x0f;
    // ceil(y) == y0+1 whenever fy>0; when fy==0 the y1 tap is multiplied by
    // 0, so any in-bounds row works -> clamp instead of ceilf. Same for x.
    const int y1 = min(y0 + 1, S - 1);
    const int x1 = min(x0 + 1, S - 1);
    const float fy = y - y0f;          // row fraction  (reference "fx")
    const float fx = x - x0f;          // col fraction  (reference "fy")

    // inputs4 index for (b, yy, xx, lane_c): ((b*S + yy)*S + xx)*32 + lane_c
    const int base = (b * S * S) * CVEC + lane_c;
    const int r0 = base + y0 * (S * CVEC);
    const int r1 = base + y1 * (S * CVEC);

    const float4 v00 = inputs4[r0 + x0 * CVEC];
    const float4 v01 = inputs4[r0 + x1 * CVEC];
    const float4 v10 = inputs4[r1 + x0 * CVEC];
    const float4 v11 = inputs4[r1 + x1 * CVEC];

    // Match reference order: lerp along x (ref "fy"), then along y (ref "fx").
    float4 vt, vb, o;
    vt.x = v00.x + (v01.x - v00.x) * fx;
    vt.y = v00.y + (v01.y - v00.y) * fx;
    vt.z = v00.z + (v01.z - v00.z) * fx;
    vt.w = v00.w + (v01.w - v00.w) * fx;
    vb.x = v10.x + (v11.x - v10.x) * fx;
    vb.y = v10.y + (v11.y - v10.y) * fx;
    vb.z = v10.z + (v11.z - v10.z) * fx;
    vb.w = v10.w + (v11.w - v10.w) * fx;
    o.x = vt.x + (vb.x - vt.x) * fy;
    o.y = vt.y + (vb.y - vt.y) * fy;
    o.z = vt.z + (vb.z - vt.z) * fy;
    o.w = vt.w + (vb.w - vt.w) * fy;

    // Streaming output: nontemporal so it doesn't evict the input row window
    // from the per-XCD L2 (the 4x tap reuse lives there).
    union { float4 f4; f32x4 v; } u;
    u.f4 = o;
    __builtin_nontemporal_store(u.v, (f32x4*)&out4[(long long)pix * CVEC + lane_c]);
}

extern "C" void kernel_launch(void* const* d_in, const int* in_sizes, int n_in,
                              void* d_out, int out_size, void* d_ws, size_t ws_size,
                              hipStream_t stream) {
    const float2* offsets2 = (const float2*)d_in[0];
    const float4* inputs4  = (const float4*)d_in[1];
    float4*       out4     = (float4*)d_out;

    const int B = in_sizes[0] / (S * S * 2);   // = 16
    const int total_pix = B * S * S;           // 262144
    const int blocks = total_pix / PIX_PER_BLOCK;  // 32768, divisible by 8
    const int blocks_per_xcd = blocks / NXCD;

    resample_kernel<<<blocks, 256, 0, stream>>>(offsets2, inputs4, out4,
                                                blocks_per_xcd);
}

// Round 3
// 233.669 us; speedup vs baseline: 1.0415x; 1.0415x over previous
//
#include <hip/hip_runtime.h>

// Bilinear resample: inputs (B,S,S,C) fp32, offsets (B,S,S,2) fp32 -> out (B,S,S,C)
// B=16, S=128, C=128.
//
// Revision: latency-bound fix. rocprof showed 87 us with HBM at 29% of peak,
// VALU 13%, no pipe saturated -> wave lifetime ~10k cycles dominated by two
// serial memory round-trips (offsets -> taps) with only 4 loads in flight.
// Change: 2 pixels per thread (16 px/block): both offset loads issued
// together, then all 8 tap loads in flight, then compute. Halves serial
// round-trips per unit work, doubles bytes-in-flight per wave.
// Also reverts the round-0 XCD swizzle (measured regression; L3 is shared so
// cross-XCD reuse was already absorbed).

constexpr int S = 128;
constexpr int CVEC = 32;           // C/4 = 128/4 float4 groups per pixel
constexpr int PIX_PER_BLOCK = 16;  // 8 pixel-groups x 2 pixels each

typedef float f32x4 __attribute__((ext_vector_type(4)));

__device__ __forceinline__ void tap_setup(int pix, int lane_c, float2 off,
                                          int& i00, int& i01, int& i10, int& i11,
                                          float& fy, float& fx)
{
    const int j   = pix & (S - 1);
    const int rem = pix >> 7;          // b*S + i
    const int i   = rem & (S - 1);
    const int b   = rem >> 7;

    float y = fminf(fmaxf((float)i + off.x, 0.0f), (float)(S - 1));
    float x = fminf(fmaxf((float)j + off.y, 0.0f), (float)(S - 1));

    const float y0f = floorf(y);
    const float x0f = floorf(x);
    const int y0 = (int)y0f;
    const int x0 = (int)x0f;
    // ceil == floor+1 whenever frac>0; when frac==0 that tap is weighted by 0,
    // so clamp replaces ceilf exactly (keeps last row/col in bounds).
    const int y1 = min(y0 + 1, S - 1);
    const int x1 = min(x0 + 1, S - 1);
    fy = y - y0f;                      // row fraction  (reference "fx")
    fx = x - x0f;                      // col fraction  (reference "fy")

    const int base = (b * S * S) * CVEC + lane_c;
    const int r0 = base + y0 * (S * CVEC);
    const int r1 = base + y1 * (S * CVEC);
    i00 = r0 + x0 * CVEC;
    i01 = r0 + x1 * CVEC;
    i10 = r1 + x0 * CVEC;
    i11 = r1 + x1 * CVEC;
}

__device__ __forceinline__ float4 bilerp(float4 v00, float4 v01,
                                         float4 v10, float4 v11,
                                         float fy, float fx)
{
    float4 vt, vb, o;
    vt.x = v00.x + (v01.x - v00.x) * fx;
    vt.y = v00.y + (v01.y - v00.y) * fx;
    vt.z = v00.z + (v01.z - v00.z) * fx;
    vt.w = v00.w + (v01.w - v00.w) * fx;
    vb.x = v10.x + (v11.x - v10.x) * fx;
    vb.y = v10.y + (v11.y - v10.y) * fx;
    vb.z = v10.z + (v11.z - v10.z) * fx;
    vb.w = v10.w + (v11.w - v10.w) * fx;
    o.x = vt.x + (vb.x - vt.x) * fy;
    o.y = vt.y + (vb.y - vt.y) * fy;
    o.z = vt.z + (vb.z - vt.z) * fy;
    o.w = vt.w + (vb.w - vt.w) * fy;
    return o;
}

__global__ __launch_bounds__(256) void resample_kernel(
    const float2* __restrict__ offsets2, // (B*S*S) float2
    const float4* __restrict__ inputs4,  // (B, S, S, C/4) as float4
    float4* __restrict__ out4)           // (B, S, S, C/4)
{
    const int tid    = threadIdx.x;
    const int lane_c = tid & 31;       // channel-group index (0..31)
    const int pg     = tid >> 5;       // pixel-group (0..7)
    const int pix0   = blockIdx.x * PIX_PER_BLOCK + pg;
    const int pix1   = pix0 + 8;

    // Both offset loads issued back-to-back: one round-trip, not two.
    const float2 off0 = offsets2[pix0];
    const float2 off1 = offsets2[pix1];

    int a00, a01, a10, a11; float fy0, fx0;
    int b00, b01, b10, b11; float fy1, fx1;
    tap_setup(pix0, lane_c, off0, a00, a01, a10, a11, fy0, fx0);
    tap_setup(pix1, lane_c, off1, b00, b01, b10, b11, fy1, fx1);

    // All 8 tap loads in flight before any use.
    const float4 va00 = inputs4[a00];
    const float4 va01 = inputs4[a01];
    const float4 va10 = inputs4[a10];
    const float4 va11 = inputs4[a11];
    const float4 vb00 = inputs4[b00];
    const float4 vb01 = inputs4[b01];
    const float4 vb10 = inputs4[b10];
    const float4 vb11 = inputs4[b11];

    const float4 o0 = bilerp(va00, va01, va10, va11, fy0, fx0);
    const float4 o1 = bilerp(vb00, vb01, vb10, vb11, fy1, fx1);

    // Streaming output: nontemporal so 128 MiB of writes don't evict the
    // L3-resident input (FETCH_SIZE=66MB < input shows residency is working).
    union { float4 f4; f32x4 v; } u0, u1;
    u0.f4 = o0;
    u1.f4 = o1;
    __builtin_nontemporal_store(u0.v, (f32x4*)&out4[(long long)pix0 * CVEC + lane_c]);
    __builtin_nontemporal_store(u1.v, (f32x4*)&out4[(long long)pix1 * CVEC + lane_c]);
}

extern "C" void kernel_launch(void* const* d_in, const int* in_sizes, int n_in,
                              void* d_out, int out_size, void* d_ws, size_t ws_size,
                              hipStream_t stream) {
    const float2* offsets2 = (const float2*)d_in[0];
    const float4* inputs4  = (const float4*)d_in[1];
    float4*       out4     = (float4*)d_out;

    const int B = in_sizes[0] / (S * S * 2);       // = 16
    const int total_pix = B * S * S;               // 262144
    const int blocks = total_pix / PIX_PER_BLOCK;  // 16384

    resample_kernel<<<blocks, 256, 0, stream>>>(offsets2, inputs4, out4);
}